// Round 13
// baseline (137.668 us; speedup 1.0000x reference)
//
#include <hip/hip_runtime.h>
#include <stdint.h>

#define C 128
#define ALPHA_F 0.1f
#define ONE_MINUS_ALPHA 0.9f
// beta = log(THETA/LAYER + 1) = log(1.25)
#define BETA_F 0.22314355131420976f
#define ONE_MINUS_BETA 0.7768564486857902f

typedef __attribute__((ext_vector_type(8))) short bf16x8;
typedef __attribute__((ext_vector_type(4))) float f32x4;

__device__ inline float bf2f(unsigned short u) {
    union { unsigned int i; float f; } c;
    c.i = ((unsigned int)u) << 16;
    return c.f;
}
__device__ inline unsigned short f2bf(float f) {
    union { float f; unsigned int i; } c;
    c.f = f;
    unsigned int r = (c.i + 0x7FFFu + ((c.i >> 16) & 1u)) >> 16;  // RNE
    return (unsigned short)r;
}

// ---- init: zero cnt + cursor + V = (1-beta)*I + beta*W^T (bf16 Vb[j][k]) ----
__global__ void k_init(const float* __restrict__ W, unsigned short* __restrict__ Vb,
                       int* __restrict__ cnt, int* __restrict__ gcur, int n) {
    int i = blockIdx.x * 256 + threadIdx.x;
    if (i == 0) *gcur = 0;
    if (i < n) cnt[i] = 0;
    if (i < C * C) {
        int j = i >> 7;   // W row = output index
        int c = i & 127;  // k index
        float v = BETA_F * W[i] + ((j == c) ? ONE_MINUS_BETA : 0.f);
        Vb[i] = f2bf(v);
    }
}

// hist + rank capture: the atomic doubles as the placement rank.
__global__ void k_hist(const int* __restrict__ dst, int* __restrict__ cnt,
                       int* __restrict__ rank, int e) {
    int i = blockIdx.x * blockDim.x + threadIdx.x;
    if (i < e) rank[i] = atomicAdd(&cnt[dst[i]], 1);
}

// segment allocation via wave-aggregated bump allocator: wave prefix-sum of
// cnt + ONE atomicAdd per wave on a global cursor. Segment placement varies
// run-to-run but per-segment content order (rank) is unchanged.
__global__ __launch_bounds__(256)
void k_alloc(const int* __restrict__ cnt, int* __restrict__ gcur,
             int4* __restrict__ meta, int* __restrict__ row_ptr,
             float* __restrict__ dinv, int n) {
    int i = blockIdx.x * 256 + threadIdx.x;
    int lane = threadIdx.x & 63;
    int v = (i < n) ? cnt[i] : 0;

    int pre = v;  // inclusive wave prefix sum
    #pragma unroll
    for (int off = 1; off < 64; off <<= 1) {
        int t = __shfl_up(pre, off, 64);
        if (lane >= off) pre += t;
    }
    int wtotal = __shfl(pre, 63, 64);
    int wbase = 0;
    if (lane == 63) wbase = atomicAdd(gcur, wtotal);
    wbase = __shfl(wbase, 63, 64);

    if (i < n) {
        int rp = wbase + pre - v;              // exclusive within wave + base
        float dv = rsqrtf((float)(v + 1));     // deg includes self-loop
        meta[i]    = make_int4(rp, v, __float_as_int(dv), 0);
        row_ptr[i] = rp;
        dinv[i]    = dv;
    }
}

// merged place + ybf: blocks [0,eb) place edges (no atomics); rest build y.
__global__ void k_pl_ybf(const int* __restrict__ src, const int* __restrict__ dst,
                         const int* __restrict__ row_ptr, const int* __restrict__ rank,
                         int* __restrict__ sorted_src, int e,
                         const float* __restrict__ x, const float* __restrict__ dinv,
                         unsigned short* __restrict__ y, int n, int eb) {
    int bid = blockIdx.x;
    if (bid < eb) {
        int i = bid * 256 + threadIdx.x;
        if (i < e) {
            int d = dst[i];
            int pos = row_ptr[d] + rank[i];
            sorted_src[pos] = src[i];
        }
    } else {
        int t = (bid - eb) * 256 + threadIdx.x;
        int total = n * 32;
        if (t < total) {
            int i = t >> 5;
            float dv = dinv[i];
            float4 v = ((const float4*)x)[t];
            ushort4 o;
            o.x = f2bf(v.x * dv);
            o.y = f2bf(v.y * dv);
            o.z = f2bf(v.z * dv);
            o.w = f2bf(v.w * dv);
            ((ushort4*)y)[t] = o;
        }
    }
}

// ---------------- gather + alpha-blend -> s (bf16 ws or fp32 d_out) --------
__global__ __launch_bounds__(256)
void k_gather(const unsigned short* __restrict__ y, const float* __restrict__ x0,
              const int* __restrict__ sorted_src, const int4* __restrict__ meta,
              float* __restrict__ soutf, unsigned short* __restrict__ soutb,
              int mode, int n) {
    int tid  = threadIdx.x;
    int l32  = tid & 31;
    int base = tid & 32;
    int node = blockIdx.x * 8 + (tid >> 5);
    if (node >= n) return;

    const ushort4* y4 = (const ushort4*)y;

    int4 md   = meta[node];
    int start = md.x;
    int len   = md.y;
    float dv  = __int_as_float(md.z);
    float4 xv = ((const float4*)x0)[(size_t)node * 32 + l32];

    int m = (len < 32) ? len : 32;
    int eidx = (l32 < m) ? sorted_src[start + l32] : node;  // pad = self

    bool b1 = 1 < m, b2 = 2 < m, b3 = 3 < m;
    bool b4 = 4 < m, b5 = 5 < m, b6 = 6 < m, b7 = 7 < m;
    int s0 = __shfl(eidx, base + 0, 64);
    int s1 = __shfl(eidx, base + (b1 ? 1 : 0), 64);
    int s2 = __shfl(eidx, base + (b2 ? 2 : 0), 64);
    int s3 = __shfl(eidx, base + (b3 ? 3 : 0), 64);
    int s4 = __shfl(eidx, base + (b4 ? 4 : 0), 64);
    int s5 = __shfl(eidx, base + (b5 ? 5 : 0), 64);
    int s6 = __shfl(eidx, base + (b6 ? 6 : 0), 64);
    int s7 = __shfl(eidx, base + (b7 ? 7 : 0), 64);
    ushort4 v0 = y4[(size_t)s0 * 32 + l32];
    ushort4 v1 = y4[(size_t)s1 * 32 + l32];
    ushort4 v2 = y4[(size_t)s2 * 32 + l32];
    ushort4 v3 = y4[(size_t)s3 * 32 + l32];
    ushort4 v4 = y4[(size_t)s4 * 32 + l32];
    ushort4 v5 = y4[(size_t)s5 * 32 + l32];
    ushort4 v6 = y4[(size_t)s6 * 32 + l32];
    ushort4 v7 = y4[(size_t)s7 * 32 + l32];
    ushort4 vs = y4[(size_t)node * 32 + l32];   // self-loop row

    float w0 = (0 < m) ? 1.f : 0.f, w1 = b1 ? 1.f : 0.f, w2 = b2 ? 1.f : 0.f, w3 = b3 ? 1.f : 0.f;
    float w4 = b4 ? 1.f : 0.f, w5 = b5 ? 1.f : 0.f, w6 = b6 ? 1.f : 0.f, w7 = b7 ? 1.f : 0.f;

    float4 acc;
    acc.x = bf2f(vs.x) + w0 * bf2f(v0.x) + w1 * bf2f(v1.x) + w2 * bf2f(v2.x) + w3 * bf2f(v3.x)
                       + w4 * bf2f(v4.x) + w5 * bf2f(v5.x) + w6 * bf2f(v6.x) + w7 * bf2f(v7.x);
    acc.y = bf2f(vs.y) + w0 * bf2f(v0.y) + w1 * bf2f(v1.y) + w2 * bf2f(v2.y) + w3 * bf2f(v3.y)
                       + w4 * bf2f(v4.y) + w5 * bf2f(v5.y) + w6 * bf2f(v6.y) + w7 * bf2f(v7.y);
    acc.z = bf2f(vs.z) + w0 * bf2f(v0.z) + w1 * bf2f(v1.z) + w2 * bf2f(v2.z) + w3 * bf2f(v3.z)
                       + w4 * bf2f(v4.z) + w5 * bf2f(v5.z) + w6 * bf2f(v6.z) + w7 * bf2f(v7.z);
    acc.w = bf2f(vs.w) + w0 * bf2f(v0.w) + w1 * bf2f(v1.w) + w2 * bf2f(v2.w) + w3 * bf2f(v3.w)
                       + w4 * bf2f(v4.w) + w5 * bf2f(v5.w) + w6 * bf2f(v6.w) + w7 * bf2f(v7.w);

    for (int j = 8; j < m; j += 4) {
        bool c1 = (j + 1) < m, c2 = (j + 2) < m, c3 = (j + 3) < m;
        int t0 = __shfl(eidx, base + j, 64);
        int t1 = __shfl(eidx, base + (c1 ? j + 1 : j), 64);
        int t2 = __shfl(eidx, base + (c2 ? j + 2 : j), 64);
        int t3 = __shfl(eidx, base + (c3 ? j + 3 : j), 64);
        ushort4 u0 = y4[(size_t)t0 * 32 + l32];
        ushort4 u1 = y4[(size_t)t1 * 32 + l32];
        ushort4 u2 = y4[(size_t)t2 * 32 + l32];
        ushort4 u3 = y4[(size_t)t3 * 32 + l32];
        float q1 = c1 ? 1.f : 0.f, q2 = c2 ? 1.f : 0.f, q3 = c3 ? 1.f : 0.f;
        acc.x += bf2f(u0.x) + q1 * bf2f(u1.x) + q2 * bf2f(u2.x) + q3 * bf2f(u3.x);
        acc.y += bf2f(u0.y) + q1 * bf2f(u1.y) + q2 * bf2f(u2.y) + q3 * bf2f(u3.y);
        acc.z += bf2f(u0.z) + q1 * bf2f(u1.z) + q2 * bf2f(u2.z) + q3 * bf2f(u3.z);
        acc.w += bf2f(u0.w) + q1 * bf2f(u1.w) + q2 * bf2f(u2.w) + q3 * bf2f(u3.w);
    }

    for (int j = 32; j < len; ++j) {     // rare: degree > 32
        int t0 = sorted_src[start + j];
        ushort4 u0 = y4[(size_t)t0 * 32 + l32];
        acc.x += bf2f(u0.x);
        acc.y += bf2f(u0.y);
        acc.z += bf2f(u0.z);
        acc.w += bf2f(u0.w);
    }

    float4 s;
    s.x = ONE_MINUS_ALPHA * (dv * acc.x) + ALPHA_F * xv.x;
    s.y = ONE_MINUS_ALPHA * (dv * acc.y) + ALPHA_F * xv.y;
    s.z = ONE_MINUS_ALPHA * (dv * acc.z) + ALPHA_F * xv.z;
    s.w = ONE_MINUS_ALPHA * (dv * acc.w) + ALPHA_F * xv.w;

    if (mode) {
        unsigned long long pk =
            (unsigned long long)f2bf(s.x)
          | ((unsigned long long)f2bf(s.y) << 16)
          | ((unsigned long long)f2bf(s.z) << 32)
          | ((unsigned long long)f2bf(s.w) << 48);
        __builtin_nontemporal_store(
            pk, (unsigned long long*)(soutb + (size_t)node * C + l32 * 4));
    } else {
        ((float4*)soutf)[(size_t)node * 32 + l32] = s;
    }
}

// ---------------- MFMA GEMM (LDS-staged, 128-row tile): out = s @ V + b*beta --
// 512 threads / 8 waves per block; wlds 32KB + slds 32KB -> 2 blocks/CU.
// 16B-granule XOR swizzle (g ^= row&7) -> conflict-free ds_read_b128.
__global__ __launch_bounds__(512)
void k_out(const float* __restrict__ sinf, const unsigned short* __restrict__ sinb,
           const unsigned short* __restrict__ Vb, const float* __restrict__ bias,
           float* __restrict__ out, int mode, int n) {
    __shared__ unsigned short wlds[128 * 128];  // 32 KB
    __shared__ unsigned short slds[128 * 128];  // 32 KB

    int tid  = threadIdx.x;
    int row0 = blockIdx.x * 128;

    const uint4* Vb16 = (const uint4*)Vb;
    for (int i = tid; i < 2048; i += 512) {
        int j = i >> 4;
        int g = i & 15;
        uint4 v = Vb16[i];
        *(uint4*)&wlds[j * 128 + (g ^ (j & 7)) * 8] = v;
    }

    if (mode) {
        const uint4* sb16 = (const uint4*)sinb;
        for (int i = tid; i < 2048; i += 512) {
            int r = i >> 4;
            int g = i & 15;
            int grow = row0 + r;
            uint4 v = make_uint4(0, 0, 0, 0);
            if (grow < n) v = sb16[(size_t)grow * 16 + g];
            *(uint4*)&slds[r * 128 + (g ^ (r & 7)) * 8] = v;
        }
    } else {
        for (int i = tid; i < 2048; i += 512) {
            int r = i >> 4;
            int g = i & 15;
            int grow = row0 + r;
            union { unsigned short u[8]; uint4 v; } pk;
            if (grow < n) {
                const float* p = sinf + (size_t)grow * C + g * 8;
                float4 aa = *(const float4*)p;
                float4 bb = *(const float4*)(p + 4);
                pk.u[0] = f2bf(aa.x); pk.u[1] = f2bf(aa.y);
                pk.u[2] = f2bf(aa.z); pk.u[3] = f2bf(aa.w);
                pk.u[4] = f2bf(bb.x); pk.u[5] = f2bf(bb.y);
                pk.u[6] = f2bf(bb.z); pk.u[7] = f2bf(bb.w);
            } else {
                pk.v = make_uint4(0, 0, 0, 0);
            }
            *(uint4*)&slds[r * 128 + (g ^ (r & 7)) * 8] = pk.v;
        }
    }
    __syncthreads();

    int w    = tid >> 6;       // 0..7: wave owns rows w*16..w*16+15
    int lane = tid & 63;
    int l16  = lane & 15;
    int h    = lane >> 4;
    int arow = w * 16 + l16;

    f32x4 acc[8];
    #pragma unroll
    for (int t = 0; t < 8; ++t) acc[t] = (f32x4){0.f, 0.f, 0.f, 0.f};

    #pragma unroll
    for (int k0 = 0; k0 < 128; k0 += 32) {
        int ga = ((k0 >> 3) + h) ^ (arow & 7);
        bf16x8 a = *(const bf16x8*)&slds[arow * 128 + ga * 8];
        #pragma unroll
        for (int t = 0; t < 8; ++t) {
            int brow = t * 16 + l16;
            int gb = ((k0 >> 3) + h) ^ (brow & 7);
            bf16x8 b = *(const bf16x8*)&wlds[brow * 128 + gb * 8];
            acc[t] = __builtin_amdgcn_mfma_f32_16x16x32_bf16(a, b, acc[t], 0, 0, 0);
        }
    }

    #pragma unroll
    for (int t = 0; t < 8; ++t) {
        int j  = t * 16 + l16;
        float bj = BETA_F * bias[j];
        #pragma unroll
        for (int e2 = 0; e2 < 4; ++e2) {
            int grow = row0 + w * 16 + h * 4 + e2;
            if (grow < n) {
                __builtin_nontemporal_store(acc[t][e2] + bj, &out[(size_t)grow * C + j]);
            }
        }
    }
}

extern "C" void kernel_launch(void* const* d_in, const int* in_sizes, int n_in,
                              void* d_out, int out_size, void* d_ws, size_t ws_size,
                              hipStream_t stream) {
    const float* x   = (const float*)d_in[0];
    const float* x0  = (const float*)d_in[1];
    const float* W   = (const float*)d_in[2];
    const float* b   = (const float*)d_in[3];
    const int*   ei  = (const int*)d_in[4];

    int n = in_sizes[0] / C;
    int e = in_sizes[4] / 2;
    const int* src = ei;
    const int* dst = ei + e;

    int*   cnt        = (int*)d_ws;                    // n
    float* dinv       = (float*)(cnt + n);             // n
    int*   gcur       = (int*)(dinv + n);              // 512 (alignment pad)
    int4*  meta       = (int4*)(gcur + 512);           // n (16B aligned)
    int*   row_ptr    = (int*)(meta + n);              // n
    int*   rank       = row_ptr + n;                   // e
    int*   sorted_src = rank + e;                      // e
    unsigned short* Vb   = (unsigned short*)(sorted_src + e);
    unsigned short* y    = Vb + C * C;                 // n*C
    unsigned short* sb16 = y + (size_t)n * C;          // n*C

    size_t need = (size_t)((char*)(sb16 + (size_t)n * C) - (char*)d_ws);
    int mode = (ws_size >= need) ? 1 : 0;

    float* out = (float*)d_out;

    int nb  = (n + 255) / 256;
    int eb  = (e + 255) / 256;
    int ybg = (n * 32 + 255) / 256;

    k_init  <<<nb, 256, 0, stream>>>(W, Vb, cnt, gcur, n);
    k_hist  <<<eb, 256, 0, stream>>>(dst, cnt, rank, e);
    k_alloc <<<nb, 256, 0, stream>>>(cnt, gcur, meta, row_ptr, dinv, n);
    k_pl_ybf<<<eb + ybg, 256, 0, stream>>>(src, dst, row_ptr, rank, sorted_src, e,
                                           x, dinv, y, n, eb);
    k_gather<<<(n + 7) / 8, 256, 0, stream>>>(y, x0, sorted_src, meta,
                                              out, sb16, mode, n);
    k_out   <<<(n + 127) / 128, 512, 0, stream>>>(out, sb16, Vb, b, out, mode, n);
}

// Round 14
// 127.233 us; speedup vs baseline: 1.0820x; 1.0820x over previous
//
#include <hip/hip_runtime.h>
#include <stdint.h>

#define C 128
#define ALPHA_F 0.1f
#define ONE_MINUS_ALPHA 0.9f
// beta = log(THETA/LAYER + 1) = log(1.25)
#define BETA_F 0.22314355131420976f
#define ONE_MINUS_BETA 0.7768564486857902f

typedef __attribute__((ext_vector_type(8))) short bf16x8;
typedef __attribute__((ext_vector_type(4))) float f32x4;

__device__ inline float bf2f(unsigned short u) {
    union { unsigned int i; float f; } c;
    c.i = ((unsigned int)u) << 16;
    return c.f;
}
__device__ inline unsigned short f2bf(float f) {
    union { float f; unsigned int i; } c;
    c.f = f;
    unsigned int r = (c.i + 0x7FFFu + ((c.i >> 16) & 1u)) >> 16;  // RNE
    return (unsigned short)r;
}

// ---- init: zero cnt + V = (1-beta)*I + beta*W^T, stored Vb[j][k] bf16 ----
__global__ void k_init(const float* __restrict__ W, unsigned short* __restrict__ Vb,
                       int* __restrict__ cnt, int n) {
    int i = blockIdx.x * 256 + threadIdx.x;
    if (i < n) cnt[i] = 0;
    if (i < C * C) {
        int j = i >> 7;   // W row = output index
        int c = i & 127;  // k index
        float v = BETA_F * W[i] + ((j == c) ? ONE_MINUS_BETA : 0.f);
        Vb[i] = f2bf(v);
    }
}

// hist + rank capture: the atomic doubles as the placement rank.
__global__ void k_hist(const int* __restrict__ dst, int* __restrict__ cnt,
                       int* __restrict__ rank, int e) {
    int i = blockIdx.x * blockDim.x + threadIdx.x;
    if (i < e) rank[i] = atomicAdd(&cnt[dst[i]], 1);
}

__global__ __launch_bounds__(256)
void k_scan_a(const int* __restrict__ cnt, int* __restrict__ part, int n) {
    __shared__ int s[256];
    int t = threadIdx.x;
    int i = blockIdx.x * 256 + t;
    s[t] = (i < n) ? cnt[i] : 0;
    __syncthreads();
    for (int off = 128; off > 0; off >>= 1) {
        if (t < off) s[t] += s[t + off];
        __syncthreads();
    }
    if (t == 0) part[blockIdx.x] = s[0];
}

// merged scan_b + scan_c
__global__ __launch_bounds__(256)
void k_scan_bc(const int* __restrict__ cnt, const int* __restrict__ part,
               int4* __restrict__ meta, int* __restrict__ row_ptr,
               float* __restrict__ dinv, int n) {
    __shared__ int a[256];
    __shared__ int b[256];
    int t   = threadIdx.x;
    int bid = blockIdx.x;

    int local = 0;
    for (int k = t; k < bid; k += 256) local += part[k];
    a[t] = local;
    __syncthreads();
    for (int off = 128; off > 0; off >>= 1) {
        if (t < off) a[t] += a[t + off];
        __syncthreads();
    }
    int blockoff = a[0];
    __syncthreads();

    int i = bid * 256 + t;
    int v = (i < n) ? cnt[i] : 0;
    a[t] = v;
    __syncthreads();
    int* cur = a;
    int* nxt = b;
    for (int off = 1; off < 256; off <<= 1) {
        nxt[t] = cur[t] + ((t >= off) ? cur[t - off] : 0);
        __syncthreads();
        int* tmp = cur; cur = nxt; nxt = tmp;
    }
    if (i < n) {
        int rp = blockoff + cur[t] - v;
        float dv = rsqrtf((float)(v + 1));     // deg includes self-loop
        meta[i]    = make_int4(rp, v, __float_as_int(dv), 0);
        row_ptr[i] = rp;
        dinv[i]    = dv;
    }
}

// merged place + ybf: blocks [0,eb) place edges (no atomics); rest build y.
__global__ void k_pl_ybf(const int* __restrict__ src, const int* __restrict__ dst,
                         const int* __restrict__ row_ptr, const int* __restrict__ rank,
                         int* __restrict__ sorted_src, int e,
                         const float* __restrict__ x, const float* __restrict__ dinv,
                         unsigned short* __restrict__ y, int n, int eb) {
    int bid = blockIdx.x;
    if (bid < eb) {
        int i = bid * 256 + threadIdx.x;
        if (i < e) {
            int d = dst[i];
            int pos = row_ptr[d] + rank[i];
            sorted_src[pos] = src[i];
        }
    } else {
        int t = (bid - eb) * 256 + threadIdx.x;
        int total = n * 32;
        if (t < total) {
            int i = t >> 5;
            float dv = dinv[i];
            float4 v = ((const float4*)x)[t];
            ushort4 o;
            o.x = f2bf(v.x * dv);
            o.y = f2bf(v.y * dv);
            o.z = f2bf(v.z * dv);
            o.w = f2bf(v.w * dv);
            ((ushort4*)y)[t] = o;
        }
    }
}

// per-node accumulate: 8 weight-clamped up-front loads + 4-wide batches to 32
// + uniform tail. eidx holds this half-wave's preloaded edge list.
__device__ __forceinline__ float4 acc_node(const ushort4* __restrict__ y4,
                                           const int* __restrict__ ss,
                                           int node, int start, int len,
                                           int eidx, int l32, int base) {
    int m = (len < 32) ? len : 32;
    bool b1 = 1 < m, b2 = 2 < m, b3 = 3 < m;
    bool b4 = 4 < m, b5 = 5 < m, b6 = 6 < m, b7 = 7 < m;
    int s0 = __shfl(eidx, base + 0, 64);
    int s1 = __shfl(eidx, base + (b1 ? 1 : 0), 64);
    int s2 = __shfl(eidx, base + (b2 ? 2 : 0), 64);
    int s3 = __shfl(eidx, base + (b3 ? 3 : 0), 64);
    int s4 = __shfl(eidx, base + (b4 ? 4 : 0), 64);
    int s5 = __shfl(eidx, base + (b5 ? 5 : 0), 64);
    int s6 = __shfl(eidx, base + (b6 ? 6 : 0), 64);
    int s7 = __shfl(eidx, base + (b7 ? 7 : 0), 64);
    ushort4 v0 = y4[(size_t)s0 * 32 + l32];
    ushort4 v1 = y4[(size_t)s1 * 32 + l32];
    ushort4 v2 = y4[(size_t)s2 * 32 + l32];
    ushort4 v3 = y4[(size_t)s3 * 32 + l32];
    ushort4 v4 = y4[(size_t)s4 * 32 + l32];
    ushort4 v5 = y4[(size_t)s5 * 32 + l32];
    ushort4 v6 = y4[(size_t)s6 * 32 + l32];
    ushort4 v7 = y4[(size_t)s7 * 32 + l32];
    ushort4 vs = y4[(size_t)node * 32 + l32];   // self-loop row

    float w0 = (0 < m) ? 1.f : 0.f, w1 = b1 ? 1.f : 0.f, w2 = b2 ? 1.f : 0.f, w3 = b3 ? 1.f : 0.f;
    float w4 = b4 ? 1.f : 0.f, w5 = b5 ? 1.f : 0.f, w6 = b6 ? 1.f : 0.f, w7 = b7 ? 1.f : 0.f;

    float4 acc;
    acc.x = bf2f(vs.x) + w0 * bf2f(v0.x) + w1 * bf2f(v1.x) + w2 * bf2f(v2.x) + w3 * bf2f(v3.x)
                       + w4 * bf2f(v4.x) + w5 * bf2f(v5.x) + w6 * bf2f(v6.x) + w7 * bf2f(v7.x);
    acc.y = bf2f(vs.y) + w0 * bf2f(v0.y) + w1 * bf2f(v1.y) + w2 * bf2f(v2.y) + w3 * bf2f(v3.y)
                       + w4 * bf2f(v4.y) + w5 * bf2f(v5.y) + w6 * bf2f(v6.y) + w7 * bf2f(v7.y);
    acc.z = bf2f(vs.z) + w0 * bf2f(v0.z) + w1 * bf2f(v1.z) + w2 * bf2f(v2.z) + w3 * bf2f(v3.z)
                       + w4 * bf2f(v4.z) + w5 * bf2f(v5.z) + w6 * bf2f(v6.z) + w7 * bf2f(v7.z);
    acc.w = bf2f(vs.w) + w0 * bf2f(v0.w) + w1 * bf2f(v1.w) + w2 * bf2f(v2.w) + w3 * bf2f(v3.w)
                       + w4 * bf2f(v4.w) + w5 * bf2f(v5.w) + w6 * bf2f(v6.w) + w7 * bf2f(v7.w);

    for (int j = 8; j < m; j += 4) {
        bool c1 = (j + 1) < m, c2 = (j + 2) < m, c3 = (j + 3) < m;
        int t0 = __shfl(eidx, base + j, 64);
        int t1 = __shfl(eidx, base + (c1 ? j + 1 : j), 64);
        int t2 = __shfl(eidx, base + (c2 ? j + 2 : j), 64);
        int t3 = __shfl(eidx, base + (c3 ? j + 3 : j), 64);
        ushort4 u0 = y4[(size_t)t0 * 32 + l32];
        ushort4 u1 = y4[(size_t)t1 * 32 + l32];
        ushort4 u2 = y4[(size_t)t2 * 32 + l32];
        ushort4 u3 = y4[(size_t)t3 * 32 + l32];
        float q1 = c1 ? 1.f : 0.f, q2 = c2 ? 1.f : 0.f, q3 = c3 ? 1.f : 0.f;
        acc.x += bf2f(u0.x) + q1 * bf2f(u1.x) + q2 * bf2f(u2.x) + q3 * bf2f(u3.x);
        acc.y += bf2f(u0.y) + q1 * bf2f(u1.y) + q2 * bf2f(u2.y) + q3 * bf2f(u3.y);
        acc.z += bf2f(u0.z) + q1 * bf2f(u1.z) + q2 * bf2f(u2.z) + q3 * bf2f(u3.z);
        acc.w += bf2f(u0.w) + q1 * bf2f(u1.w) + q2 * bf2f(u2.w) + q3 * bf2f(u3.w);
    }

    for (int j = 32; j < len; ++j) {     // rare: degree > 32
        int t0 = ss[start + j];
        ushort4 u0 = y4[(size_t)t0 * 32 + l32];
        acc.x += bf2f(u0.x);
        acc.y += bf2f(u0.y);
        acc.z += bf2f(u0.z);
        acc.w += bf2f(u0.w);
    }
    return acc;
}

// ---------------- gather + alpha-blend -> s (bf16 ws or fp32 d_out) --------
// 2 nodes per HALF-WAVE, front-loads paired: both metas, both edge lists,
// both x0 rows (NT) issue together; node1's y-loads overlap node0's VALU.
__global__ __launch_bounds__(256)
void k_gather(const unsigned short* __restrict__ y, const float* __restrict__ x0,
              const int* __restrict__ sorted_src, const int4* __restrict__ meta,
              float* __restrict__ soutf, unsigned short* __restrict__ soutb,
              int mode, int n) {
    int tid  = threadIdx.x;
    int l32  = tid & 31;
    int base = tid & 32;
    int hw   = tid >> 5;                  // 0..7 half-wave in block
    int node0 = blockIdx.x * 16 + hw * 2;
    if (node0 >= n) return;
    int node1 = node0 + 1;
    bool ok1 = node1 < n;
    int vn1 = ok1 ? node1 : node0;

    const ushort4* y4 = (const ushort4*)y;
    const f32x4* x04 = (const f32x4*)x0;

    // paired front-loads (all independent)
    int4 md0 = meta[node0];
    int4 md1 = meta[vn1];
    int m0 = (md0.y < 32) ? md0.y : 32;
    int m1 = (md1.y < 32) ? md1.y : 32;
    int e0 = (l32 < m0) ? sorted_src[md0.x + l32] : node0;
    int e1 = (l32 < m1) ? sorted_src[md1.x + l32] : vn1;
    f32x4 xv0 = __builtin_nontemporal_load(x04 + (size_t)node0 * 32 + l32);
    f32x4 xv1 = __builtin_nontemporal_load(x04 + (size_t)vn1 * 32 + l32);

    float4 a0 = acc_node(y4, sorted_src, node0, md0.x, md0.y, e0, l32, base);
    float4 a1 = acc_node(y4, sorted_src, vn1,   md1.x, md1.y, e1, l32, base);

    float dv0 = __int_as_float(md0.z);
    float dv1 = __int_as_float(md1.z);

    float4 s0, s1;
    s0.x = ONE_MINUS_ALPHA * (dv0 * a0.x) + ALPHA_F * xv0.x;
    s0.y = ONE_MINUS_ALPHA * (dv0 * a0.y) + ALPHA_F * xv0.y;
    s0.z = ONE_MINUS_ALPHA * (dv0 * a0.z) + ALPHA_F * xv0.z;
    s0.w = ONE_MINUS_ALPHA * (dv0 * a0.w) + ALPHA_F * xv0.w;
    s1.x = ONE_MINUS_ALPHA * (dv1 * a1.x) + ALPHA_F * xv1.x;
    s1.y = ONE_MINUS_ALPHA * (dv1 * a1.y) + ALPHA_F * xv1.y;
    s1.z = ONE_MINUS_ALPHA * (dv1 * a1.z) + ALPHA_F * xv1.z;
    s1.w = ONE_MINUS_ALPHA * (dv1 * a1.w) + ALPHA_F * xv1.w;

    if (mode) {
        unsigned long long p0 =
            (unsigned long long)f2bf(s0.x)
          | ((unsigned long long)f2bf(s0.y) << 16)
          | ((unsigned long long)f2bf(s0.z) << 32)
          | ((unsigned long long)f2bf(s0.w) << 48);
        __builtin_nontemporal_store(
            p0, (unsigned long long*)(soutb + (size_t)node0 * C + l32 * 4));
        if (ok1) {
            unsigned long long p1 =
                (unsigned long long)f2bf(s1.x)
              | ((unsigned long long)f2bf(s1.y) << 16)
              | ((unsigned long long)f2bf(s1.z) << 32)
              | ((unsigned long long)f2bf(s1.w) << 48);
            __builtin_nontemporal_store(
                p1, (unsigned long long*)(soutb + (size_t)node1 * C + l32 * 4));
        }
    } else {
        ((float4*)soutf)[(size_t)node0 * 32 + l32] = s0;
        if (ok1) ((float4*)soutf)[(size_t)node1 * 32 + l32] = s1;
    }
}

// ---------------- MFMA GEMM (LDS-staged): out = s @ V + beta*b ----------------
// V folds the (1-beta)*s blend. Both operands LDS-staged, 16B-granule XOR
// swizzle (g ^= row&7) -> conflict-free ds_read_b128 for MFMA fragments.
// (LDS staging matters because it converts 16-row-scattered global B-loads
// into ds_read_b128 — NOT an occupancy effect; round-11 no-LDS variant: 50us.)
__global__ __launch_bounds__(256)
void k_out(const float* __restrict__ sinf, const unsigned short* __restrict__ sinb,
           const unsigned short* __restrict__ Vb, const float* __restrict__ bias,
           float* __restrict__ out, int mode, int n) {
    __shared__ unsigned short wlds[128 * 128];  // 32 KB
    __shared__ unsigned short slds[64 * 128];   // 16 KB

    int tid  = threadIdx.x;
    int row0 = blockIdx.x * 64;

    const uint4* Vb16 = (const uint4*)Vb;
    for (int i = tid; i < 2048; i += 256) {
        int j = i >> 4;
        int g = i & 15;
        uint4 v = Vb16[i];
        *(uint4*)&wlds[j * 128 + (g ^ (j & 7)) * 8] = v;
    }

    if (mode) {
        const uint4* sb16 = (const uint4*)sinb;
        for (int i = tid; i < 1024; i += 256) {
            int r = i >> 4;
            int g = i & 15;
            int grow = row0 + r;
            uint4 v = make_uint4(0, 0, 0, 0);
            if (grow < n) v = sb16[(size_t)grow * 16 + g];
            *(uint4*)&slds[r * 128 + (g ^ (r & 7)) * 8] = v;
        }
    } else {
        for (int i = tid; i < 1024; i += 256) {
            int r = i >> 4;
            int g = i & 15;
            int grow = row0 + r;
            union { unsigned short u[8]; uint4 v; } pk;
            if (grow < n) {
                const float* p = sinf + (size_t)grow * C + g * 8;
                float4 aa = *(const float4*)p;
                float4 bb = *(const float4*)(p + 4);
                pk.u[0] = f2bf(aa.x); pk.u[1] = f2bf(aa.y);
                pk.u[2] = f2bf(aa.z); pk.u[3] = f2bf(aa.w);
                pk.u[4] = f2bf(bb.x); pk.u[5] = f2bf(bb.y);
                pk.u[6] = f2bf(bb.z); pk.u[7] = f2bf(bb.w);
            } else {
                pk.v = make_uint4(0, 0, 0, 0);
            }
            *(uint4*)&slds[r * 128 + (g ^ (r & 7)) * 8] = pk.v;
        }
    }
    __syncthreads();

    int w    = tid >> 6;
    int lane = tid & 63;
    int l16  = lane & 15;
    int h    = lane >> 4;
    int arow = w * 16 + l16;

    f32x4 acc[8];
    #pragma unroll
    for (int t = 0; t < 8; ++t) acc[t] = (f32x4){0.f, 0.f, 0.f, 0.f};

    #pragma unroll
    for (int k0 = 0; k0 < 128; k0 += 32) {
        int ga = ((k0 >> 3) + h) ^ (arow & 7);
        bf16x8 a = *(const bf16x8*)&slds[arow * 128 + ga * 8];
        #pragma unroll
        for (int t = 0; t < 8; ++t) {
            int brow = t * 16 + l16;
            int gb = ((k0 >> 3) + h) ^ (brow & 7);
            bf16x8 b = *(const bf16x8*)&wlds[brow * 128 + gb * 8];
            acc[t] = __builtin_amdgcn_mfma_f32_16x16x32_bf16(a, b, acc[t], 0, 0, 0);
        }
    }

    #pragma unroll
    for (int t = 0; t < 8; ++t) {
        int j  = t * 16 + l16;
        float bj = BETA_F * bias[j];
        #pragma unroll
        for (int e2 = 0; e2 < 4; ++e2) {
            int grow = row0 + w * 16 + h * 4 + e2;
            if (grow < n) {
                __builtin_nontemporal_store(acc[t][e2] + bj, &out[(size_t)grow * C + j]);
            }
        }
    }
}

extern "C" void kernel_launch(void* const* d_in, const int* in_sizes, int n_in,
                              void* d_out, int out_size, void* d_ws, size_t ws_size,
                              hipStream_t stream) {
    const float* x   = (const float*)d_in[0];
    const float* x0  = (const float*)d_in[1];
    const float* W   = (const float*)d_in[2];
    const float* b   = (const float*)d_in[3];
    const int*   ei  = (const int*)d_in[4];

    int n = in_sizes[0] / C;
    int e = in_sizes[4] / 2;
    const int* src = ei;
    const int* dst = ei + e;

    int*   cnt        = (int*)d_ws;                    // n
    float* dinv       = (float*)(cnt + n);             // n
    int*   part       = (int*)(dinv + n);              // 512
    int4*  meta       = (int4*)(part + 512);           // n (16B aligned)
    int*   row_ptr    = (int*)(meta + n);              // n
    int*   rank       = row_ptr + n;                   // e
    int*   sorted_src = rank + e;                      // e
    unsigned short* Vb   = (unsigned short*)(sorted_src + e);
    unsigned short* y    = Vb + C * C;                 // n*C
    unsigned short* sb16 = y + (size_t)n * C;          // n*C

    size_t need = (size_t)((char*)(sb16 + (size_t)n * C) - (char*)d_ws);
    int mode = (ws_size >= need) ? 1 : 0;

    float* out = (float*)d_out;

    int nb  = (n + 255) / 256;
    int eb  = (e + 255) / 256;
    int ybg = (n * 32 + 255) / 256;

    k_init   <<<nb, 256, 0, stream>>>(W, Vb, cnt, n);
    k_hist   <<<eb, 256, 0, stream>>>(dst, cnt, rank, e);
    k_scan_a <<<nb, 256, 0, stream>>>(cnt, part, n);
    k_scan_bc<<<nb, 256, 0, stream>>>(cnt, part, meta, row_ptr, dinv, n);
    k_pl_ybf <<<eb + ybg, 256, 0, stream>>>(src, dst, row_ptr, rank, sorted_src, e,
                                            x, dinv, y, n, eb);
    k_gather <<<(n + 15) / 16, 256, 0, stream>>>(y, x0, sorted_src, meta,
                                                 out, sb16, mode, n);
    k_out    <<<(n + 63) / 64, 256, 0, stream>>>(out, sb16, Vb, b, out, mode, n);
}